// Round 2
// baseline (107.710 us; speedup 1.0000x reference)
//
#include <hip/hip_runtime.h>

// LELoss: scalar loss =
//   mean_B sum_D (x - decoded)^2
// + 1.1 * mean_B sum_E (encoded - latent @ rsrA^T)^2   (lambda1 + duplicated 0.1 term;
//                                                       kNN top-k is dead code)
// + 0.1 * mean_{20x20} (rsrA^T rsrA - I)^2
//
// Shapes fixed: x,decoded [8192,1024] f32; encoded [8192,128]; latent [8192,20];
// rsrA [128,20]. Output: 1 float.
//
// R3 = R2 resubmitted (R2 bench died on container acquisition, no data).
// R2 structure change vs R1 (106.0us): part B no longer goes through LDS.
// Each lane loads its rsrA row (e = gid&127) as 5 float4 = 20 VGPRs -- a
// contiguous, 16B-aligned 80B cache-hit read issued in the same VMEM burst
// as the part-A loads. This removes 10 global loads + 10 ds_writes + a
// __syncthreads + 40 ds_reads from every block's critical path. The Gram
// term keeps LDS staging but only in block 0 (block-uniform barrier).
// Timed window = 2x 256MiB harness ws-poison fills (~83us, invariant) +
// main + final; this targets main (~19 -> ~13-15us predicted).

#define BB 8192
#define DD 1024
#define EE 128
#define EEP 129                 // sAT leading-dim pad (Gram term, block 0 only)
#define II 20
#define GRID 2048
#define BLK 256
#define GSZ (GRID * BLK)        // 524288 threads; A: 4 float4-pairs/thread, B: 2 elems/thread

// Force a wave-uniform pointer into SGPRs so constant-offset loads become
// s_load (scalar path) instead of 64 redundant per-lane VMEM loads.
__device__ __forceinline__ const float* uniform_ptr(const float* p) {
    unsigned long long v = (unsigned long long)p;
    unsigned lo = __builtin_amdgcn_readfirstlane((unsigned)v);
    unsigned hi = __builtin_amdgcn_readfirstlane((unsigned)(v >> 32));
    return (const float*)(((unsigned long long)hi << 32) | lo);
}

__global__ __launch_bounds__(BLK, 6) void leloss_main(
    const float* __restrict__ x,
    const float* __restrict__ encoded,
    const float* __restrict__ latent,
    const float* __restrict__ decoded,
    const float* __restrict__ rsrA,
    float* __restrict__ partials)
{
    __shared__ float sAT[II * EEP];   // Gram staging, used by block 0 only
    __shared__ float sred[4];

    const int tid = threadIdx.x;
    const int gid = blockIdx.x * BLK + tid;

    // ---- Part A loads: 4 independent float4 pairs, all in flight at once ----
    const float4* __restrict__ x4 = (const float4*)x;
    const float4* __restrict__ d4 = (const float4*)decoded;
    float4 a0 = x4[gid];
    float4 b0 = d4[gid];
    float4 a1 = x4[gid + GSZ];
    float4 b1 = d4[gid + GSZ];
    float4 a2 = x4[gid + 2 * GSZ];
    float4 b2 = d4[gid + 2 * GSZ];
    float4 a3 = x4[gid + 3 * GSZ];
    float4 b3 = d4[gid + 3 * GSZ];

    // ---- Part B loads: coalesced encoded + per-lane rsrA row (cache-hit) ----
    const float enc0 = encoded[gid];
    const float enc1 = encoded[gid + GSZ];

    const int e = gid & (EE - 1);
    // rsrA row e: 20 floats, 80B, 16B-aligned (80 = 5*16). L1-resident after warm.
    const float4* __restrict__ r4 = (const float4*)(rsrA + e * II);
    float4 t0 = r4[0];
    float4 t1 = r4[1];
    float4 t2 = r4[2];
    float4 t3 = r4[3];
    float4 t4 = r4[4];

    // ---- Gram term: block 0 only; LDS staging + block-uniform barrier ----
    float accC = 0.f;
    if (blockIdx.x == 0) {
        for (int t = tid; t < EE * II; t += BLK) {
            int ee = t / II, k = t - ee * II;
            sAT[k * EEP + ee] = rsrA[t];
        }
        __syncthreads();
        for (int t = tid; t < II * II; t += BLK) {
            const int i2 = t / II, j2 = t - i2 * II;
            float g = 0.f;
#pragma unroll 8
            for (int eidx = 0; eidx < EE; ++eidx)
                g = fmaf(sAT[i2 * EEP + eidx], sAT[j2 * EEP + eidx], g);
            if (i2 == j2) g -= 1.f;
            accC = fmaf(g, g, accC);
        }
    }

    // ---- Part A compute (waits only on the first 8 loads; rest stay in flight) ----
    float accA = 0.f;
    {
        float d;
        d = a0.x - b0.x; accA = fmaf(d, d, accA);
        d = a0.y - b0.y; accA = fmaf(d, d, accA);
        d = a0.z - b0.z; accA = fmaf(d, d, accA);
        d = a0.w - b0.w; accA = fmaf(d, d, accA);
        d = a1.x - b1.x; accA = fmaf(d, d, accA);
        d = a1.y - b1.y; accA = fmaf(d, d, accA);
        d = a1.z - b1.z; accA = fmaf(d, d, accA);
        d = a1.w - b1.w; accA = fmaf(d, d, accA);
        d = a2.x - b2.x; accA = fmaf(d, d, accA);
        d = a2.y - b2.y; accA = fmaf(d, d, accA);
        d = a2.z - b2.z; accA = fmaf(d, d, accA);
        d = a2.w - b2.w; accA = fmaf(d, d, accA);
        d = a3.x - b3.x; accA = fmaf(d, d, accA);
        d = a3.y - b3.y; accA = fmaf(d, d, accA);
        d = a3.z - b3.z; accA = fmaf(d, d, accA);
        d = a3.w - b3.w; accA = fmaf(d, d, accA);
    }

    // ---- Part B: two (b,e) elements per thread; rsrA row in regs, latent via s_load ----
    float accB = 0.f;
    {
        const int brow = gid >> 7;   // uniform per wave (wave spans half of E=128)
        const float* __restrict__ l0 = uniform_ptr(latent + brow * II);
        const float* __restrict__ l1 = uniform_ptr(latent + (brow + (GSZ >> 7)) * II);
        float z0, z1;
        z0 = t0.x * l0[0];            z1 = t0.x * l1[0];
        z0 = fmaf(t0.y, l0[1], z0);   z1 = fmaf(t0.y, l1[1], z1);
        z0 = fmaf(t0.z, l0[2], z0);   z1 = fmaf(t0.z, l1[2], z1);
        z0 = fmaf(t0.w, l0[3], z0);   z1 = fmaf(t0.w, l1[3], z1);
        z0 = fmaf(t1.x, l0[4], z0);   z1 = fmaf(t1.x, l1[4], z1);
        z0 = fmaf(t1.y, l0[5], z0);   z1 = fmaf(t1.y, l1[5], z1);
        z0 = fmaf(t1.z, l0[6], z0);   z1 = fmaf(t1.z, l1[6], z1);
        z0 = fmaf(t1.w, l0[7], z0);   z1 = fmaf(t1.w, l1[7], z1);
        z0 = fmaf(t2.x, l0[8], z0);   z1 = fmaf(t2.x, l1[8], z1);
        z0 = fmaf(t2.y, l0[9], z0);   z1 = fmaf(t2.y, l1[9], z1);
        z0 = fmaf(t2.z, l0[10], z0);  z1 = fmaf(t2.z, l1[10], z1);
        z0 = fmaf(t2.w, l0[11], z0);  z1 = fmaf(t2.w, l1[11], z1);
        z0 = fmaf(t3.x, l0[12], z0);  z1 = fmaf(t3.x, l1[12], z1);
        z0 = fmaf(t3.y, l0[13], z0);  z1 = fmaf(t3.y, l1[13], z1);
        z0 = fmaf(t3.z, l0[14], z0);  z1 = fmaf(t3.z, l1[14], z1);
        z0 = fmaf(t3.w, l0[15], z0);  z1 = fmaf(t3.w, l1[15], z1);
        z0 = fmaf(t4.x, l0[16], z0);  z1 = fmaf(t4.x, l1[16], z1);
        z0 = fmaf(t4.y, l0[17], z0);  z1 = fmaf(t4.y, l1[17], z1);
        z0 = fmaf(t4.z, l0[18], z0);  z1 = fmaf(t4.z, l1[18], z1);
        z0 = fmaf(t4.w, l0[19], z0);  z1 = fmaf(t4.w, l1[19], z1);
        const float f0 = enc0 - z0;
        const float f1 = enc1 - z1;
        accB = fmaf(f0, f0, f1 * f1);
    }

    float total = accA * (1.0f / BB)
                + accB * (1.1f / BB)
                + accC * (0.1f / (II * II));

    // ---- block reduce: wave64 shuffle, 4 waves via LDS, plain store ----
#pragma unroll
    for (int off = 32; off > 0; off >>= 1)
        total += __shfl_down(total, off, 64);
    if ((tid & 63) == 0) sred[tid >> 6] = total;
    __syncthreads();
    if (tid == 0)
        partials[blockIdx.x] = sred[0] + sred[1] + sred[2] + sred[3];
}

__global__ __launch_bounds__(BLK) void leloss_final(
    const float* __restrict__ partials,
    float* __restrict__ out)
{
    __shared__ float sred[4];
    const int tid = threadIdx.x;

    // 2048 partials = 512 float4; 2 per thread, all in flight at once.
    const float4* __restrict__ p4 = (const float4*)partials;
    float4 v0 = p4[tid];
    float4 v1 = p4[tid + BLK];
    float acc = ((v0.x + v0.y) + (v0.z + v0.w))
              + ((v1.x + v1.y) + (v1.z + v1.w));

#pragma unroll
    for (int off = 32; off > 0; off >>= 1)
        acc += __shfl_down(acc, off, 64);
    if ((tid & 63) == 0) sred[tid >> 6] = acc;
    __syncthreads();
    if (tid == 0) out[0] = sred[0] + sred[1] + sred[2] + sred[3];
}

extern "C" void kernel_launch(void* const* d_in, const int* in_sizes, int n_in,
                              void* d_out, int out_size, void* d_ws, size_t ws_size,
                              hipStream_t stream) {
    const float* x       = (const float*)d_in[0];
    const float* encoded = (const float*)d_in[1];
    const float* latent  = (const float*)d_in[2];
    const float* decoded = (const float*)d_in[3];
    const float* rsrA    = (const float*)d_in[4];
    float* out      = (float*)d_out;
    float* partials = (float*)d_ws;   // 2048 floats; every slot written by K1

    leloss_main<<<GRID, BLK, 0, stream>>>(x, encoded, latent, decoded, rsrA, partials);
    leloss_final<<<1, BLK, 0, stream>>>(partials, out);
}